// Round 3
// baseline (544.420 us; speedup 1.0000x reference)
//
#include <hip/hip_runtime.h>
#include <hip/hip_bf16.h>
#include <cstdint>
#include <cstddef>

#define NPIX 4096   // H*W = 64*64
#define CIN  256
#define CQK  32
#define BSZ  4
#define MT   32     // m rows per fused block
#define NT   64     // n columns per tile

typedef __attribute__((ext_vector_type(8))) short          bf16x8;
typedef __attribute__((ext_vector_type(4))) float          f32x4;
typedef __attribute__((ext_vector_type(8))) unsigned short u16x8;

static __device__ inline unsigned short f2bf(float f) {
    __hip_bfloat16 h = __float2bfloat16(f);   // RNE
    unsigned short u;
    __builtin_memcpy(&u, &h, 2);
    return u;
}

static __device__ inline void gl2lds16(const void* g, void* l) {
    // 16B-per-lane direct global->LDS; LDS dest is wave-uniform base + lane*16
    __builtin_amdgcn_global_load_lds(
        (const __attribute__((address_space(1))) unsigned int*)g,
        (__attribute__((address_space(3))) unsigned int*)l,
        16, 0, 0);
}

// ---------------- Kernel 1 (fallback only): fp32 projection ----------------
__global__ __launch_bounds__(256) void proj_kernel(
    const float* __restrict__ x, const float* __restrict__ W,
    const float* __restrict__ bias, float* __restrict__ y, int Cout)
{
    __shared__ float Wl[8][CIN];
    const int t  = threadIdx.x;
    const int n0 = blockIdx.x * 1024;
    const int o0 = blockIdx.y * 8;
    const int b  = blockIdx.z;

    #pragma unroll
    for (int j = 0; j < 8; ++j) {
        int flat = t + 256 * j;
        int row = flat >> 8, col = flat & 255;
        Wl[row][col] = W[(o0 + row) * CIN + col];
    }
    __syncthreads();

    float acc[8][4];
    #pragma unroll
    for (int o = 0; o < 8; ++o)
        #pragma unroll
        for (int i = 0; i < 4; ++i) acc[o][i] = 0.f;

    const float* xb = x + ((size_t)b * CIN) * NPIX + n0 + t * 4;
    #pragma unroll 4
    for (int c = 0; c < CIN; ++c) {
        float4 xv = *(const float4*)(xb + (size_t)c * NPIX);
        #pragma unroll
        for (int o = 0; o < 8; ++o) {
            float w = Wl[o][c];
            acc[o][0] = fmaf(w, xv.x, acc[o][0]);
            acc[o][1] = fmaf(w, xv.y, acc[o][1]);
            acc[o][2] = fmaf(w, xv.z, acc[o][2]);
            acc[o][3] = fmaf(w, xv.w, acc[o][3]);
        }
    }
    #pragma unroll
    for (int o = 0; o < 8; ++o) {
        float bb = bias[o0 + o];
        float4 r = { acc[o][0] + bb, acc[o][1] + bb,
                     acc[o][2] + bb, acc[o][3] + bb };
        *(float4*)(y + ((size_t)(b * Cout + o0 + o)) * NPIX + n0 + t * 4) = r;
    }
}

// ---------------- Kernel 1a: fused q+k projection (fp32 out) ---------------
__global__ __launch_bounds__(256) void proj_qk_kernel(
    const float* __restrict__ x,
    const float* __restrict__ wq, const float* __restrict__ bq,
    const float* __restrict__ wk, const float* __restrict__ bk,
    float* __restrict__ qout, float* __restrict__ kout)
{
    __shared__ float Wl[CIN][12];   // [c][o], padded: 48B row, 16B-aligned
    const int t  = threadIdx.x;
    const int n0 = blockIdx.x * 512;
    const int og = blockIdx.y * 8;
    const int b  = blockIdx.z;
    const bool isK = og >= CQK;               // block-uniform
    const float* W    = isK ? wk : wq;
    const float* bias = isK ? bk : bq;
    float* y          = isK ? kout : qout;
    const int o0      = isK ? og - CQK : og;

    #pragma unroll
    for (int j = 0; j < 8; ++j) {
        int flat = t + 256 * j;
        int o = flat >> 8, c = flat & 255;
        Wl[c][o] = W[(o0 + o) * CIN + c];
    }
    __syncthreads();

    float acc[8][2];
    #pragma unroll
    for (int o = 0; o < 8; ++o) { acc[o][0] = 0.f; acc[o][1] = 0.f; }

    const float* xb = x + ((size_t)b * CIN) * NPIX + n0 + t * 2;
    #pragma unroll 4
    for (int c = 0; c < CIN; ++c) {
        float2 xv = *(const float2*)(xb + (size_t)c * NPIX);
        f32x4 w0 = *(const f32x4*)&Wl[c][0];   // lane-uniform: LDS broadcast
        f32x4 w1 = *(const f32x4*)&Wl[c][4];
        float wv[8] = { w0[0], w0[1], w0[2], w0[3],
                        w1[0], w1[1], w1[2], w1[3] };
        #pragma unroll
        for (int o = 0; o < 8; ++o) {
            acc[o][0] = fmaf(wv[o], xv.x, acc[o][0]);
            acc[o][1] = fmaf(wv[o], xv.y, acc[o][1]);
        }
    }
    #pragma unroll
    for (int o = 0; o < 8; ++o) {
        float bb = bias[o0 + o];
        float2 r = { acc[o][0] + bb, acc[o][1] + bb };
        *(float2*)(y + ((size_t)(b * CQK + o0 + o)) * NPIX + n0 + t * 2) = r;
    }
}

// ---------------- Kernel 1b: v projection, bf16 out ------------------------
__global__ __launch_bounds__(256) void proj_v_bf16_kernel(
    const float* __restrict__ x, const float* __restrict__ W,
    const float* __restrict__ bias, unsigned short* __restrict__ y)
{
    __shared__ float Wl[CIN][20];   // [c][o], padded: 80B row, 16B-aligned
    const int t  = threadIdx.x;
    const int n0 = blockIdx.x * 512;
    const int o0 = blockIdx.y * 16;
    const int b  = blockIdx.z;

    #pragma unroll
    for (int j = 0; j < 16; ++j) {
        int flat = t + 256 * j;
        int o = flat >> 8, c = flat & 255;
        Wl[c][o] = W[(o0 + o) * CIN + c];
    }
    __syncthreads();

    float acc[16][2];
    #pragma unroll
    for (int o = 0; o < 16; ++o) { acc[o][0] = 0.f; acc[o][1] = 0.f; }

    const float* xb = x + ((size_t)b * CIN) * NPIX + n0 + t * 2;
    #pragma unroll 2
    for (int c = 0; c < CIN; ++c) {
        float2 xv = *(const float2*)(xb + (size_t)c * NPIX);
        f32x4 w0 = *(const f32x4*)&Wl[c][0];
        f32x4 w1 = *(const f32x4*)&Wl[c][4];
        f32x4 w2 = *(const f32x4*)&Wl[c][8];
        f32x4 w3 = *(const f32x4*)&Wl[c][12];
        float wv[16] = { w0[0], w0[1], w0[2], w0[3],
                         w1[0], w1[1], w1[2], w1[3],
                         w2[0], w2[1], w2[2], w2[3],
                         w3[0], w3[1], w3[2], w3[3] };
        #pragma unroll
        for (int o = 0; o < 16; ++o) {
            acc[o][0] = fmaf(wv[o], xv.x, acc[o][0]);
            acc[o][1] = fmaf(wv[o], xv.y, acc[o][1]);
        }
    }
    #pragma unroll
    for (int o = 0; o < 16; ++o) {
        float bb = bias[o0 + o];
        ushort2 r;
        r.x = f2bf(acc[o][0] + bb);
        r.y = f2bf(acc[o][1] + bb);
        *(ushort2*)(y + ((size_t)(b * CIN + o0 + o)) * NPIX + n0 + t * 2) = r;
    }
}

// ---------------- Kernel 2 (fallback): energy + softmax --------------------
__global__ __launch_bounds__(512) void energy_softmax_kernel(
    const float* __restrict__ q, const float* __restrict__ k,
    float* __restrict__ at_map)
{
    __shared__ float kk[CQK][12];
    __shared__ float wredM[8][8];
    __shared__ float wredS[8][8];
    const int t  = threadIdx.x;
    const int m0 = blockIdx.x * 8;
    const int b  = blockIdx.y;
    const int lane = t & 63, wid = t >> 6;

    if (t < 256) {
        int c = t >> 3, mi = t & 7;
        kk[c][mi] = k[((size_t)(b * CQK + c)) * NPIX + m0 + mi];
    }
    __syncthreads();

    float s[8][8];
    #pragma unroll
    for (int mi = 0; mi < 8; ++mi)
        #pragma unroll
        for (int i = 0; i < 8; ++i) s[mi][i] = 0.f;

    const float* qb = q + ((size_t)b * CQK) * NPIX + t * 8;
    #pragma unroll 2
    for (int c = 0; c < CQK; ++c) {
        float4 q0 = *(const float4*)(qb + (size_t)c * NPIX);
        float4 q1 = *(const float4*)(qb + (size_t)c * NPIX + 4);
        f32x4 k0 = *(const f32x4*)&kk[c][0];
        f32x4 k1 = *(const f32x4*)&kk[c][4];
        float kv[8] = { k0[0], k0[1], k0[2], k0[3],
                        k1[0], k1[1], k1[2], k1[3] };
        #pragma unroll
        for (int mi = 0; mi < 8; ++mi) {
            float w = kv[mi];
            s[mi][0] = fmaf(w, q0.x, s[mi][0]);
            s[mi][1] = fmaf(w, q0.y, s[mi][1]);
            s[mi][2] = fmaf(w, q0.z, s[mi][2]);
            s[mi][3] = fmaf(w, q0.w, s[mi][3]);
            s[mi][4] = fmaf(w, q1.x, s[mi][4]);
            s[mi][5] = fmaf(w, q1.y, s[mi][5]);
            s[mi][6] = fmaf(w, q1.z, s[mi][6]);
            s[mi][7] = fmaf(w, q1.w, s[mi][7]);
        }
    }

    #pragma unroll
    for (int mi = 0; mi < 8; ++mi) {
        float mx = s[mi][0];
        #pragma unroll
        for (int i = 1; i < 8; ++i) mx = fmaxf(mx, s[mi][i]);
        #pragma unroll
        for (int off = 1; off < 64; off <<= 1)
            mx = fmaxf(mx, __shfl_xor(mx, off, 64));
        if (lane == 0) wredM[mi][wid] = mx;
    }
    __syncthreads();

    #pragma unroll
    for (int mi = 0; mi < 8; ++mi) {
        float bmx = wredM[mi][0];
        #pragma unroll
        for (int w = 1; w < 8; ++w) bmx = fmaxf(bmx, wredM[mi][w]);
        float sum = 0.f;
        #pragma unroll
        for (int i = 0; i < 8; ++i) {
            s[mi][i] = __expf(s[mi][i] - bmx);
            sum += s[mi][i];
        }
        #pragma unroll
        for (int off = 1; off < 64; off <<= 1)
            sum += __shfl_xor(sum, off, 64);
        if (lane == 0) wredS[mi][wid] = sum;
    }
    __syncthreads();

    #pragma unroll
    for (int mi = 0; mi < 8; ++mi) {
        float bsum = 0.f;
        #pragma unroll
        for (int w = 0; w < 8; ++w) bsum += wredS[mi][w];
        float inv = 1.f / bsum;
        size_t rowoff = ((size_t)(b * NPIX) + m0 + mi) * NPIX + t * 8;
        float4 r0 = { s[mi][0]*inv, s[mi][1]*inv, s[mi][2]*inv, s[mi][3]*inv };
        float4 r1 = { s[mi][4]*inv, s[mi][5]*inv, s[mi][6]*inv, s[mi][7]*inv };
        *(float4*)(at_map + rowoff)     = r0;
        *(float4*)(at_map + rowoff + 4) = r1;
    }
}

// ---------------- Kernel 2+3 fused: energy+softmax+PV (flash-style) --------
// Per block: b fixed, 32 m-rows. Pass 1: stream n computing s=q.k (fp32),
// online max/sum per m (wave-local: each wave owns 8 m's). Pass 2: recompute
// s, write NORMALIZED fp32 at_map (only unavoidable HBM stream), p->bf16 in
// LDS, MFMA vs V tile (global_load_lds + XOR-granule swizzle). P never
// touches HBM (-268 MB traffic vs split pipeline). 512 blocks = 2/CU.
__global__ __launch_bounds__(256) void fused_attn_kernel(
    const float* __restrict__ q,              // [B,CQK,N] fp32
    const float* __restrict__ k,              // [B,CQK,N] fp32
    const unsigned short* __restrict__ v,     // [B,CIN,N] bf16
    const float* __restrict__ x, const float* __restrict__ gptr,
    float* __restrict__ at_map, float* __restrict__ out)
{
    __shared__ __align__(16) unsigned short Vs[CIN * NT];   // 32 KB [c][n] swz
    __shared__ __align__(16) float          Qs[2][CQK * NT];// 16 KB [c][n] dbuf
    __shared__ __align__(16) unsigned short Ps[MT * 72];    // 4.5 KB [m][n+pad]
    __shared__ float Ks[CQK][MT];                           // 4 KB [c][m]
    __shared__ float MaxS[MT], InvS[MT];

    const int t = threadIdx.x, lane = t & 63, w = t >> 6;

    // bijective XCD decode: 512 blocks; XCDs {b, b+4} split b's 128 m-tiles
    const int gid = blockIdx.x;
    const int xcd = gid & 7, slot = gid >> 3;
    const int b = xcd & 3;
    const int m0 = (slot + ((xcd >> 2) << 6)) * MT;

    // softmax-role: thread owns m-pair mp (2 rows) x n-quad nq (4 cols)
    const int nq = lane & 15;
    const int mp = w * 4 + (lane >> 4);     // 0..15, wave-local
    const int mA = 2 * mp, mB = 2 * mp + 1;
    // MFMA-role
    const int l15 = lane & 15, q4 = lane >> 4;
    const int wc = w * 64;
    const int xo0 = (q4 ^ (l15 & 7)) * 8;
    const int xo1 = ((q4 ^ 4) ^ (l15 & 7)) * 8;
    // V staging lane mapping (8 rows x 8 16B-granules per instr, XOR swizzle)
    const int lrow = lane >> 3;
    const int glog = (lane & 7) ^ lrow;

    const float* qbase = q + (size_t)b * CQK * NPIX;
    const unsigned short* vbase = v + (size_t)b * CIN * NPIX;

    // ---- K panel -> LDS ----
    for (int i = t; i < CQK * MT; i += 256) {
        int c = i >> 5, m = i & 31;
        Ks[c][m] = k[((size_t)(b * CQK + c)) * NPIX + m0 + m];
    }
    // ---- prologue: stage q tile 0 into Qs[0] ----
    #pragma unroll
    for (int jj = 0; jj < 2; ++jj) {
        int c0 = w * 8 + jj * 4;
        gl2lds16(qbase + (size_t)(c0 + (lane >> 4)) * NPIX + (lane & 15) * 4,
                 &Qs[0][c0 * NT]);
    }
    __syncthreads();

    // ================= PASS 1: online max / sum =================
    float M0 = -1e30f, M1 = -1e30f, S0 = 0.f, S1 = 0.f;

    for (int tile = 0; tile < NPIX / NT; ++tile) {
        const int cur = tile & 1;
        if (tile + 1 < NPIX / NT) {
            #pragma unroll
            for (int jj = 0; jj < 2; ++jj) {
                int c0 = w * 8 + jj * 4;
                gl2lds16(qbase + (size_t)(c0 + (lane >> 4)) * NPIX
                               + (tile + 1) * NT + (lane & 15) * 4,
                         &Qs[cur ^ 1][c0 * NT]);
            }
        }
        float sA[4] = {0.f,0.f,0.f,0.f}, sB[4] = {0.f,0.f,0.f,0.f};
        #pragma unroll 8
        for (int c = 0; c < CQK; ++c) {
            f32x4 qv = *(const f32x4*)&Qs[cur][c * NT + nq * 4];
            float2 kv = *(const float2*)&Ks[c][mA];
            #pragma unroll
            for (int i = 0; i < 4; ++i) {
                sA[i] = fmaf(kv.x, qv[i], sA[i]);
                sB[i] = fmaf(kv.y, qv[i], sB[i]);
            }
        }
        float tA = fmaxf(fmaxf(sA[0], sA[1]), fmaxf(sA[2], sA[3]));
        float tB = fmaxf(fmaxf(sB[0], sB[1]), fmaxf(sB[2], sB[3]));
        if (tA > M0) { S0 *= __expf(M0 - tA); M0 = tA; }
        if (tB > M1) { S1 *= __expf(M1 - tB); M1 = tB; }
        #pragma unroll
        for (int i = 0; i < 4; ++i) {
            S0 += __expf(sA[i] - M0);
            S1 += __expf(sB[i] - M1);
        }
        __syncthreads();   // qbuf rotate + drain prefetch
    }

    // merge (M,S) across the 16 lanes of each m-group (butterfly, width 16)
    #pragma unroll
    for (int off = 1; off < 16; off <<= 1) {
        float Mo = __shfl_xor(M0, off, 16);
        float So = __shfl_xor(S0, off, 16);
        float Mn = fmaxf(M0, Mo);
        S0 = S0 * __expf(M0 - Mn) + So * __expf(Mo - Mn);
        M0 = Mn;
        Mo = __shfl_xor(M1, off, 16);
        So = __shfl_xor(S1, off, 16);
        Mn = fmaxf(M1, Mo);
        S1 = S1 * __expf(M1 - Mn) + So * __expf(Mo - Mn);
        M1 = Mn;
    }
    if ((lane & 15) == 0) {
        MaxS[mA] = M0; InvS[mA] = 1.f / S0;
        MaxS[mB] = M1; InvS[mB] = 1.f / S1;
    }
    // re-stage q tile 0 for pass 2
    #pragma unroll
    for (int jj = 0; jj < 2; ++jj) {
        int c0 = w * 8 + jj * 4;
        gl2lds16(qbase + (size_t)(c0 + (lane >> 4)) * NPIX + (lane & 15) * 4,
                 &Qs[0][c0 * NT]);
    }
    __syncthreads();

    const float Mh0 = MaxS[mA], Mh1 = MaxS[mB];
    const float I0  = InvS[mA], I1  = InvS[mB];

    // ================= PASS 2: at_map write + PV MFMA =================
    f32x4 acc[4][2];
    #pragma unroll
    for (int i = 0; i < 4; ++i)
        #pragma unroll
        for (int j = 0; j < 2; ++j) acc[i][j] = (f32x4)(0.0f);

    for (int tile = 0; tile < NPIX / NT; ++tile) {
        const int cur = tile & 1;
        // stage V tile (issued early; s-compute hides the latency)
        #pragma unroll
        for (int qi = 0; qi < 8; ++qi)
            gl2lds16(vbase + (size_t)(w * 64 + qi * 8 + lrow) * NPIX
                           + tile * NT + glog * 8,
                     &Vs[(w * 64 + qi * 8) * NT]);
        if (tile + 1 < NPIX / NT) {
            #pragma unroll
            for (int jj = 0; jj < 2; ++jj) {
                int c0 = w * 8 + jj * 4;
                gl2lds16(qbase + (size_t)(c0 + (lane >> 4)) * NPIX
                               + (tile + 1) * NT + (lane & 15) * 4,
                         &Qs[cur ^ 1][c0 * NT]);
            }
        }
        // recompute s (identical fp32 FMA order to pass 1)
        float sA[4] = {0.f,0.f,0.f,0.f}, sB[4] = {0.f,0.f,0.f,0.f};
        #pragma unroll 8
        for (int c = 0; c < CQK; ++c) {
            f32x4 qv = *(const f32x4*)&Qs[cur][c * NT + nq * 4];
            float2 kv = *(const float2*)&Ks[c][mA];
            #pragma unroll
            for (int i = 0; i < 4; ++i) {
                sA[i] = fmaf(kv.x, qv[i], sA[i]);
                sB[i] = fmaf(kv.y, qv[i], sB[i]);
            }
        }
        float pA[4], pB[4];
        #pragma unroll
        for (int i = 0; i < 4; ++i) {
            pA[i] = __expf(sA[i] - Mh0);
            pB[i] = __expf(sB[i] - Mh1);
        }
        // normalized fp32 at_map (dense float4 per 2 rows)
        {
            size_t rowA = ((size_t)(b * NPIX) + m0 + mA) * NPIX + tile * NT + nq * 4;
            size_t rowB = ((size_t)(b * NPIX) + m0 + mB) * NPIX + tile * NT + nq * 4;
            f32x4 wA = { pA[0]*I0, pA[1]*I0, pA[2]*I0, pA[3]*I0 };
            f32x4 wB = { pB[0]*I1, pB[1]*I1, pB[2]*I1, pB[3]*I1 };
            *(f32x4*)(at_map + rowA) = wA;
            *(f32x4*)(at_map + rowB) = wB;
        }
        // unnormalized p -> bf16 -> Ps
        {
            ushort4 ua, ub;
            ua.x = f2bf(pA[0]); ua.y = f2bf(pA[1]); ua.z = f2bf(pA[2]); ua.w = f2bf(pA[3]);
            ub.x = f2bf(pB[0]); ub.y = f2bf(pB[1]); ub.z = f2bf(pB[2]); ub.w = f2bf(pB[3]);
            *(ushort4*)&Ps[mA * 72 + nq * 4] = ua;
            *(ushort4*)&Ps[mB * 72 + nq * 4] = ub;
        }
        __syncthreads();   // Ps visible + V/q gl2lds drained
        // MFMA: O[c,m] += V[c,n] * p[m,n]
        #pragma unroll
        for (int ks = 0; ks < 2; ++ks) {
            const int xo = ks ? xo1 : xo0;
            bf16x8 af[4], bfr[2];
            #pragma unroll
            for (int i = 0; i < 4; ++i)
                af[i] = *(const bf16x8*)&Vs[(wc + i * 16 + l15) * NT + xo];
            #pragma unroll
            for (int j = 0; j < 2; ++j)
                bfr[j] = *(const bf16x8*)&Ps[(j * 16 + l15) * 72 + ks * 32 + q4 * 8];
            #pragma unroll
            for (int i = 0; i < 4; ++i)
                #pragma unroll
                for (int j = 0; j < 2; ++j)
                    acc[i][j] = __builtin_amdgcn_mfma_f32_16x16x32_bf16(
                        af[i], bfr[j], acc[i][j], 0, 0, 0);
        }
        __syncthreads();   // protect Vs/Ps before next-tile staging
    }

    // ---- epilogue: out = x + gamma*inv[m]*O.  D: row=(q4)*4+r, col=l15 ----
    const float g = gptr[0];
    float invm[2] = { InvS[l15], InvS[16 + l15] };
    #pragma unroll
    for (int i = 0; i < 4; ++i) {
        int c = wc + i * 16 + q4 * 4;
        #pragma unroll
        for (int j = 0; j < 2; ++j) {
            int m = m0 + j * 16 + l15;
            float gi = g * invm[j];
            #pragma unroll
            for (int r = 0; r < 4; ++r) {
                size_t idx = ((size_t)(b * CIN + c + r)) * NPIX + m;
                out[idx] = x[idx] + gi * acc[i][j][r];
            }
        }
    }
}

// ---------------- Kernel 3 (fallback): fp32 VALU GEMM ----------------------
__global__ __launch_bounds__(256) void sa_gemm_kernel(
    const float* __restrict__ v, const float* __restrict__ at_map,
    const float* __restrict__ x, const float* __restrict__ gptr,
    float* __restrict__ out)
{
    __shared__ float Vt[32][68];
    __shared__ float At[32][68];
    const int t  = threadIdx.x;
    const int m0 = blockIdx.x * 64;
    const int c0 = blockIdx.y * 64;
    const int b  = blockIdx.z;
    const int r  = t >> 2, qd = t & 3;
    const int tc = t & 15, tm = t >> 4;

    const float* vb = v      + ((size_t)(b * CIN  + c0 + r)) * NPIX + qd * 4;
    const float* ab = at_map + ((size_t)(b * NPIX + m0 + r)) * NPIX + qd * 4;

    float acc[4][4];
    #pragma unroll
    for (int i = 0; i < 4; ++i)
        #pragma unroll
        for (int j = 0; j < 4; ++j) acc[i][j] = 0.f;

    for (int n0 = 0; n0 < NPIX; n0 += 32) {
        float4 v0 = *(const float4*)(vb + n0);
        float4 v1 = *(const float4*)(vb + n0 + 16);
        float4 a0 = *(const float4*)(ab + n0);
        float4 a1 = *(const float4*)(ab + n0 + 16);
        Vt[qd*4+0][r] = v0.x; Vt[qd*4+1][r] = v0.y;
        Vt[qd*4+2][r] = v0.z; Vt[qd*4+3][r] = v0.w;
        Vt[16+qd*4+0][r] = v1.x; Vt[16+qd*4+1][r] = v1.y;
        Vt[16+qd*4+2][r] = v1.z; Vt[16+qd*4+3][r] = v1.w;
        At[qd*4+0][r] = a0.x; At[qd*4+1][r] = a0.y;
        At[qd*4+2][r] = a0.z; At[qd*4+3][r] = a0.w;
        At[16+qd*4+0][r] = a1.x; At[16+qd*4+1][r] = a1.y;
        At[16+qd*4+2][r] = a1.z; At[16+qd*4+3][r] = a1.w;
        __syncthreads();
        #pragma unroll
        for (int kk = 0; kk < 32; ++kk) {
            float4 a  = *(const float4*)&Vt[kk][tc * 4];
            float4 bb = *(const float4*)&At[kk][tm * 4];
            acc[0][0] = fmaf(a.x, bb.x, acc[0][0]);
            acc[0][1] = fmaf(a.x, bb.y, acc[0][1]);
            acc[0][2] = fmaf(a.x, bb.z, acc[0][2]);
            acc[0][3] = fmaf(a.x, bb.w, acc[0][3]);
            acc[1][0] = fmaf(a.y, bb.x, acc[1][0]);
            acc[1][1] = fmaf(a.y, bb.y, acc[1][1]);
            acc[1][2] = fmaf(a.y, bb.z, acc[1][2]);
            acc[1][3] = fmaf(a.y, bb.w, acc[1][3]);
            acc[2][0] = fmaf(a.z, bb.x, acc[2][0]);
            acc[2][1] = fmaf(a.z, bb.y, acc[2][1]);
            acc[2][2] = fmaf(a.z, bb.z, acc[2][2]);
            acc[2][3] = fmaf(a.z, bb.w, acc[2][3]);
            acc[3][0] = fmaf(a.w, bb.x, acc[3][0]);
            acc[3][1] = fmaf(a.w, bb.y, acc[3][1]);
            acc[3][2] = fmaf(a.w, bb.z, acc[3][2]);
            acc[3][3] = fmaf(a.w, bb.w, acc[3][3]);
        }
        __syncthreads();
    }

    const float g = *gptr;
    #pragma unroll
    for (int i = 0; i < 4; ++i) {
        size_t row = ((size_t)(b * CIN + c0 + tc * 4 + i)) * NPIX + m0 + tm * 4;
        float4 xv = *(const float4*)(x + row);
        float4 o  = { xv.x + g * acc[i][0], xv.y + g * acc[i][1],
                      xv.z + g * acc[i][2], xv.w + g * acc[i][3] };
        *(float4*)(out + row) = o;
    }
}

extern "C" void kernel_launch(void* const* d_in, const int* in_sizes, int n_in,
                              void* d_out, int out_size, void* d_ws, size_t ws_size,
                              hipStream_t stream) {
    const float* x     = (const float*)d_in[0];
    const float* wq    = (const float*)d_in[1];
    const float* bq    = (const float*)d_in[2];
    const float* wk    = (const float*)d_in[3];
    const float* bk    = (const float*)d_in[4];
    const float* wv    = (const float*)d_in[5];
    const float* bv    = (const float*)d_in[6];
    const float* gamma = (const float*)d_in[7];

    float* out    = (float*)d_out;                   // [B,C,H,W]
    float* at_map = out + (size_t)BSZ * CIN * NPIX;  // [B,N,N] fp32

    const size_t qk_elems  = (size_t)BSZ * CQK * NPIX;   // 524288
    const size_t v_elems   = (size_t)BSZ * CIN * NPIX;   // 4194304

    // fast path needs: q,k fp32 + v bf16  (no attn round-trip anymore)
    const size_t need_fast = 2 * qk_elems * 4 + v_elems * 2;

    if (ws_size >= need_fast) {
        float*          q    = (float*)d_ws;
        float*          k    = q + qk_elems;
        unsigned short* v_bf = (unsigned short*)(k + qk_elems);

        proj_qk_kernel<<<dim3(NPIX/512, 8, BSZ), 256, 0, stream>>>(
            x, wq, bq, wk, bk, q, k);
        proj_v_bf16_kernel<<<dim3(NPIX/512, CIN/16, BSZ), 256, 0, stream>>>(
            x, wv, bv, v_bf);

        fused_attn_kernel<<<dim3(512, 1, 1), 256, 0, stream>>>(
            q, k, v_bf, x, gamma, at_map, out);
    } else {
        // fallback: all-fp32 split path
        float* q = (float*)d_ws;
        float* k = q + qk_elems;
        float* v = k + qk_elems;

        proj_kernel<<<dim3(NPIX/1024, CQK/8, BSZ), 256, 0, stream>>>(x, wq, bq, q, CQK);
        proj_kernel<<<dim3(NPIX/1024, CQK/8, BSZ), 256, 0, stream>>>(x, wk, bk, k, CQK);
        proj_kernel<<<dim3(NPIX/1024, CIN/8, BSZ), 256, 0, stream>>>(x, wv, bv, v, CIN);

        energy_softmax_kernel<<<dim3(NPIX/8, BSZ), 512, 0, stream>>>(q, k, at_map);

        sa_gemm_kernel<<<dim3(NPIX/64, CIN/64, BSZ), 256, 0, stream>>>(
            v, at_map, x, gamma, out);
    }
}

// Round 5
// 506.373 us; speedup vs baseline: 1.0751x; 1.0751x over previous
//
#include <hip/hip_runtime.h>
#include <hip/hip_bf16.h>
#include <cstdint>
#include <cstddef>

#define NPIX 4096   // H*W = 64*64
#define CIN  256
#define CQK  32
#define BSZ  4
#define MT   32     // m rows per fused block
#define NT   64     // n columns per tile
#define PSW  72     // Ps row pitch (shorts)

typedef __attribute__((ext_vector_type(8))) short          bf16x8;
typedef __attribute__((ext_vector_type(4))) float          f32x4;
typedef __attribute__((ext_vector_type(8))) unsigned short u16x8;

static __device__ inline unsigned short f2bf(float f) {
    __hip_bfloat16 h = __float2bfloat16(f);   // RNE
    unsigned short u;
    __builtin_memcpy(&u, &h, 2);
    return u;
}

static __device__ inline float bf2f(unsigned short u) {
    unsigned int x = ((unsigned int)u) << 16;
    float f;
    __builtin_memcpy(&f, &x, 4);
    return f;
}

static __device__ inline void gl2lds16(const void* g, void* l) {
    // 16B-per-lane direct global->LDS; LDS dest is wave-uniform base + lane*16
    __builtin_amdgcn_global_load_lds(
        (const __attribute__((address_space(1))) unsigned int*)g,
        (__attribute__((address_space(3))) unsigned int*)l,
        16, 0, 0);
}

// ---------------- Kernel 1 (fallback only): fp32 projection ----------------
__global__ __launch_bounds__(256) void proj_kernel(
    const float* __restrict__ x, const float* __restrict__ W,
    const float* __restrict__ bias, float* __restrict__ y, int Cout)
{
    __shared__ float Wl[8][CIN];
    const int t  = threadIdx.x;
    const int n0 = blockIdx.x * 1024;
    const int o0 = blockIdx.y * 8;
    const int b  = blockIdx.z;

    #pragma unroll
    for (int j = 0; j < 8; ++j) {
        int flat = t + 256 * j;
        int row = flat >> 8, col = flat & 255;
        Wl[row][col] = W[(o0 + row) * CIN + col];
    }
    __syncthreads();

    float acc[8][4];
    #pragma unroll
    for (int o = 0; o < 8; ++o)
        #pragma unroll
        for (int i = 0; i < 4; ++i) acc[o][i] = 0.f;

    const float* xb = x + ((size_t)b * CIN) * NPIX + n0 + t * 4;
    #pragma unroll 4
    for (int c = 0; c < CIN; ++c) {
        float4 xv = *(const float4*)(xb + (size_t)c * NPIX);
        #pragma unroll
        for (int o = 0; o < 8; ++o) {
            float w = Wl[o][c];
            acc[o][0] = fmaf(w, xv.x, acc[o][0]);
            acc[o][1] = fmaf(w, xv.y, acc[o][1]);
            acc[o][2] = fmaf(w, xv.z, acc[o][2]);
            acc[o][3] = fmaf(w, xv.w, acc[o][3]);
        }
    }
    #pragma unroll
    for (int o = 0; o < 8; ++o) {
        float bb = bias[o0 + o];
        float4 r = { acc[o][0] + bb, acc[o][1] + bb,
                     acc[o][2] + bb, acc[o][3] + bb };
        *(float4*)(y + ((size_t)(b * Cout + o0 + o)) * NPIX + n0 + t * 4) = r;
    }
}

// ---------------- Kernel 1a: fused q+k projection, transposed split-bf16 ---
// Emits qt/kt in [b][n][64] layout: shorts [0..31] = bf16 hi of c=0..31,
// [32..63] = bf16 lo (residual).  MFMA fragments read 16B per lane directly.
__global__ __launch_bounds__(256) void proj_qk_t_kernel(
    const float* __restrict__ x,
    const float* __restrict__ wq, const float* __restrict__ bq,
    const float* __restrict__ wk, const float* __restrict__ bk,
    unsigned short* __restrict__ qt, unsigned short* __restrict__ kt)
{
    __shared__ float Wl[CIN][12];   // [c][o], padded
    const int t  = threadIdx.x;
    const int n0 = blockIdx.x * 512;
    const int og = blockIdx.y * 8;
    const int b  = blockIdx.z;
    const bool isK = og >= CQK;               // block-uniform
    const float* W    = isK ? wk : wq;
    const float* bias = isK ? bk : bq;
    unsigned short* y = (isK ? kt : qt) + ((size_t)b * NPIX) * 64;
    const int o0      = isK ? og - CQK : og;

    #pragma unroll
    for (int j = 0; j < 8; ++j) {
        int flat = t + 256 * j;
        int o = flat >> 8, c = flat & 255;
        Wl[c][o] = W[(o0 + o) * CIN + c];
    }
    __syncthreads();

    float acc[8][2];
    #pragma unroll
    for (int o = 0; o < 8; ++o) { acc[o][0] = 0.f; acc[o][1] = 0.f; }

    const float* xb = x + ((size_t)b * CIN) * NPIX + n0 + t * 2;
    #pragma unroll 4
    for (int c = 0; c < CIN; ++c) {
        float2 xv = *(const float2*)(xb + (size_t)c * NPIX);
        f32x4 w0 = *(const f32x4*)&Wl[c][0];   // lane-uniform: LDS broadcast
        f32x4 w1 = *(const f32x4*)&Wl[c][4];
        float wv[8] = { w0[0], w0[1], w0[2], w0[3],
                        w1[0], w1[1], w1[2], w1[3] };
        #pragma unroll
        for (int o = 0; o < 8; ++o) {
            acc[o][0] = fmaf(wv[o], xv.x, acc[o][0]);
            acc[o][1] = fmaf(wv[o], xv.y, acc[o][1]);
        }
    }
    #pragma unroll
    for (int i = 0; i < 2; ++i) {
        size_t n = (size_t)(n0 + t * 2 + i);
        u16x8 hi, lo;
        #pragma unroll
        for (int o = 0; o < 8; ++o) {
            float val = acc[o][i] + bias[o0 + o];
            unsigned short h = f2bf(val);
            hi[o] = h;
            lo[o] = f2bf(val - bf2f(h));
        }
        *(u16x8*)(y + n * 64 + o0)      = hi;
        *(u16x8*)(y + n * 64 + 32 + o0) = lo;
    }
}

// ---------------- Kernel 1b: v projection, bf16 out ------------------------
__global__ __launch_bounds__(256) void proj_v_bf16_kernel(
    const float* __restrict__ x, const float* __restrict__ W,
    const float* __restrict__ bias, unsigned short* __restrict__ y)
{
    __shared__ float Wl[CIN][20];   // [c][o], padded
    const int t  = threadIdx.x;
    const int n0 = blockIdx.x * 512;
    const int o0 = blockIdx.y * 16;
    const int b  = blockIdx.z;

    #pragma unroll
    for (int j = 0; j < 16; ++j) {
        int flat = t + 256 * j;
        int o = flat >> 8, c = flat & 255;
        Wl[c][o] = W[(o0 + o) * CIN + c];
    }
    __syncthreads();

    float acc[16][2];
    #pragma unroll
    for (int o = 0; o < 16; ++o) { acc[o][0] = 0.f; acc[o][1] = 0.f; }

    const float* xb = x + ((size_t)b * CIN) * NPIX + n0 + t * 2;
    #pragma unroll 2
    for (int c = 0; c < CIN; ++c) {
        float2 xv = *(const float2*)(xb + (size_t)c * NPIX);
        f32x4 w0 = *(const f32x4*)&Wl[c][0];
        f32x4 w1 = *(const f32x4*)&Wl[c][4];
        f32x4 w2 = *(const f32x4*)&Wl[c][8];
        f32x4 w3 = *(const f32x4*)&Wl[c][12];
        float wv[16] = { w0[0], w0[1], w0[2], w0[3],
                         w1[0], w1[1], w1[2], w1[3],
                         w2[0], w2[1], w2[2], w2[3],
                         w3[0], w3[1], w3[2], w3[3] };
        #pragma unroll
        for (int o = 0; o < 16; ++o) {
            acc[o][0] = fmaf(wv[o], xv.x, acc[o][0]);
            acc[o][1] = fmaf(wv[o], xv.y, acc[o][1]);
        }
    }
    #pragma unroll
    for (int o = 0; o < 16; ++o) {
        float bb = bias[o0 + o];
        ushort2 r;
        r.x = f2bf(acc[o][0] + bb);
        r.y = f2bf(acc[o][1] + bb);
        *(ushort2*)(y + ((size_t)(b * CIN + o0 + o)) * NPIX + n0 + t * 2) = r;
    }
}

// ---------------- Kernel 2 (fallback): energy + softmax --------------------
__global__ __launch_bounds__(512) void energy_softmax_kernel(
    const float* __restrict__ q, const float* __restrict__ k,
    float* __restrict__ at_map)
{
    __shared__ float kk[CQK][12];
    __shared__ float wredM[8][8];
    __shared__ float wredS[8][8];
    const int t  = threadIdx.x;
    const int m0 = blockIdx.x * 8;
    const int b  = blockIdx.y;
    const int lane = t & 63, wid = t >> 6;

    if (t < 256) {
        int c = t >> 3, mi = t & 7;
        kk[c][mi] = k[((size_t)(b * CQK + c)) * NPIX + m0 + mi];
    }
    __syncthreads();

    float s[8][8];
    #pragma unroll
    for (int mi = 0; mi < 8; ++mi)
        #pragma unroll
        for (int i = 0; i < 8; ++i) s[mi][i] = 0.f;

    const float* qb = q + ((size_t)b * CQK) * NPIX + t * 8;
    #pragma unroll 2
    for (int c = 0; c < CQK; ++c) {
        float4 q0 = *(const float4*)(qb + (size_t)c * NPIX);
        float4 q1 = *(const float4*)(qb + (size_t)c * NPIX + 4);
        f32x4 k0 = *(const f32x4*)&kk[c][0];
        f32x4 k1 = *(const f32x4*)&kk[c][4];
        float kv[8] = { k0[0], k0[1], k0[2], k0[3],
                        k1[0], k1[1], k1[2], k1[3] };
        #pragma unroll
        for (int mi = 0; mi < 8; ++mi) {
            float w = kv[mi];
            s[mi][0] = fmaf(w, q0.x, s[mi][0]);
            s[mi][1] = fmaf(w, q0.y, s[mi][1]);
            s[mi][2] = fmaf(w, q0.z, s[mi][2]);
            s[mi][3] = fmaf(w, q0.w, s[mi][3]);
            s[mi][4] = fmaf(w, q1.x, s[mi][4]);
            s[mi][5] = fmaf(w, q1.y, s[mi][5]);
            s[mi][6] = fmaf(w, q1.z, s[mi][6]);
            s[mi][7] = fmaf(w, q1.w, s[mi][7]);
        }
    }

    #pragma unroll
    for (int mi = 0; mi < 8; ++mi) {
        float mx = s[mi][0];
        #pragma unroll
        for (int i = 1; i < 8; ++i) mx = fmaxf(mx, s[mi][i]);
        #pragma unroll
        for (int off = 1; off < 64; off <<= 1)
            mx = fmaxf(mx, __shfl_xor(mx, off, 64));
        if (lane == 0) wredM[mi][wid] = mx;
    }
    __syncthreads();

    #pragma unroll
    for (int mi = 0; mi < 8; ++mi) {
        float bmx = wredM[mi][0];
        #pragma unroll
        for (int w = 1; w < 8; ++w) bmx = fmaxf(bmx, wredM[mi][w]);
        float sum = 0.f;
        #pragma unroll
        for (int i = 0; i < 8; ++i) {
            s[mi][i] = __expf(s[mi][i] - bmx);
            sum += s[mi][i];
        }
        #pragma unroll
        for (int off = 1; off < 64; off <<= 1)
            sum += __shfl_xor(sum, off, 64);
        if (lane == 0) wredS[mi][wid] = sum;
    }
    __syncthreads();

    #pragma unroll
    for (int mi = 0; mi < 8; ++mi) {
        float bsum = 0.f;
        #pragma unroll
        for (int w = 0; w < 8; ++w) bsum += wredS[mi][w];
        float inv = 1.f / bsum;
        size_t rowoff = ((size_t)(b * NPIX) + m0 + mi) * NPIX + t * 8;
        float4 r0 = { s[mi][0]*inv, s[mi][1]*inv, s[mi][2]*inv, s[mi][3]*inv };
        float4 r1 = { s[mi][4]*inv, s[mi][5]*inv, s[mi][6]*inv, s[mi][7]*inv };
        *(float4*)(at_map + rowoff)     = r0;
        *(float4*)(at_map + rowoff + 4) = r1;
    }
}

// ---------------- Fused: energy(MFMA split-bf16)+softmax+at_map+PV ---------
// 512 thr / 8 waves per block; block = 32 m rows, b fixed; 512 blocks.
// s = q.k on the MFMA pipe: s = qh*kh + ql*kh + qh*kl (err ~1e-3 abs).
// Wave w -> s-subtile (msub=w>>2, nsub=w&3); D-layout: lane l15 = m-local,
// regs = 4 consecutive n.  Pass 1 (barrier-free): online (M,S) per lane,
// butterfly + LDS merge.  Pass 2: s-MFMA -> exp -> Ps(ds_write_b64, m x n
// transpose) + normalized fp32 at_map float4 -> PV MFMA vs Vs (gl2lds +
// XOR-granule swizzle).  K-frags live in 8 VGPRs; Q-frags stream from L2.
__global__ __launch_bounds__(512, 4) void fused_attn_mfma(
    const unsigned short* __restrict__ qt,   // [B][N][64] bf16 hi|lo
    const unsigned short* __restrict__ kt,   // [B][N][64] bf16 hi|lo
    const unsigned short* __restrict__ v,    // [B][CIN][N] bf16
    const float* __restrict__ x, const float* __restrict__ gptr,
    float* __restrict__ at_map, float* __restrict__ out)
{
    __shared__ __align__(16) unsigned short Vs[CIN * NT];   // 32 KB
    __shared__ __align__(16) unsigned short Ps[MT * PSW];   // 4.5 KB
    __shared__ float MSred[2][4][16][2];                    // 1 KB
    __shared__ float IvS[MT];

    const int t = threadIdx.x, lane = t & 63, w = t >> 6;
    // bijective XCD decode: 512 blocks; XCDs {b, b+4} split b's 128 m-tiles
    const int gid = blockIdx.x;
    const int xcd = gid & 7, slot = gid >> 3;
    const int b  = xcd & 3;
    const int m0 = (slot + ((xcd >> 2) << 6)) * MT;

    const int l15 = lane & 15, q4 = lane >> 4;
    const int msub = w >> 2, nsub = w & 3;
    const int wc = w * 32;                 // PV c-row base for this wave
    const int lrow = lane >> 3;            // V staging: row within 8-row group
    const int glog = (lane & 7) ^ lrow;    // swizzled logical granule

    // K fragment (B operand; col = m-local = msub*16+l15), held in regs
    const unsigned short* kp =
        kt + ((size_t)(b * NPIX + m0 + msub * 16 + l15)) * 64 + q4 * 8;
    const bf16x8 khi = *(const bf16x8*)kp;
    const bf16x8 klo = *(const bf16x8*)(kp + 32);

    // Q fragment source (A operand; row = n-local = nsub*16+l15)
    const unsigned short* qp =
        qt + ((size_t)(b * NPIX) + nsub * 16 + l15) * 64 + q4 * 8;

    const unsigned short* vbase = v + (size_t)b * CIN * NPIX;

    // ================= PASS 1: online (M,S), barrier-free =================
    float M = -1e30f, S = 0.f;
    bf16x8 qh = *(const bf16x8*)qp;
    bf16x8 ql = *(const bf16x8*)(qp + 32);
    for (int tile = 0; tile < NPIX / NT; ++tile) {
        bf16x8 qh2 = qh, ql2 = ql;
        if (tile + 1 < NPIX / NT) {
            const unsigned short* p = qp + (size_t)(tile + 1) * (NT * 64);
            qh2 = *(const bf16x8*)p;
            ql2 = *(const bf16x8*)(p + 32);
        }
        f32x4 s4 = (f32x4)(0.0f);
        s4 = __builtin_amdgcn_mfma_f32_16x16x32_bf16(qh, khi, s4, 0, 0, 0);
        s4 = __builtin_amdgcn_mfma_f32_16x16x32_bf16(ql, khi, s4, 0, 0, 0);
        s4 = __builtin_amdgcn_mfma_f32_16x16x32_bf16(qh, klo, s4, 0, 0, 0);
        float mx = fmaxf(fmaxf(s4[0], s4[1]), fmaxf(s4[2], s4[3]));
        if (mx > M) { S *= __expf(M - mx); M = mx; }
        S += __expf(s4[0] - M); S += __expf(s4[1] - M);
        S += __expf(s4[2] - M); S += __expf(s4[3] - M);
        qh = qh2; ql = ql2;
    }
    // merge across the 4 q4-groups (lanes sharing the same m)
    #pragma unroll
    for (int off = 16; off < 64; off <<= 1) {
        float Mo = __shfl_xor(M, off, 64);
        float So = __shfl_xor(S, off, 64);
        float Mn = fmaxf(M, Mo);
        S = S * __expf(M - Mn) + So * __expf(Mo - Mn);
        M = Mn;
    }
    if (q4 == 0) {
        MSred[msub][nsub][l15][0] = M;
        MSred[msub][nsub][l15][1] = S;
    }
    __syncthreads();
    {   // merge across the 4 nsub waves; every lane ends with final (M, inv)
        float Mf = MSred[msub][0][l15][0], Sf = MSred[msub][0][l15][1];
        #pragma unroll
        for (int j = 1; j < 4; ++j) {
            float Mo = MSred[msub][j][l15][0], So = MSred[msub][j][l15][1];
            float Mn = fmaxf(Mf, Mo);
            Sf = Sf * __expf(Mf - Mn) + So * __expf(Mo - Mn);
            Mf = Mn;
        }
        M = Mf;
        S = 1.0f / Sf;                         // S := 1/rowsum
        if ((w == 0 || w == 4) && q4 == 0) IvS[msub * 16 + l15] = S;
    }
    __syncthreads();

    // ================= PASS 2: at_map + PV =================
    f32x4 acc[2][2];
    acc[0][0] = (f32x4)(0.0f); acc[0][1] = (f32x4)(0.0f);
    acc[1][0] = (f32x4)(0.0f); acc[1][1] = (f32x4)(0.0f);

    qh = *(const bf16x8*)qp;
    ql = *(const bf16x8*)(qp + 32);

    const size_t amrow = ((size_t)(b * NPIX + m0 + msub * 16 + l15)) * NPIX
                       + nsub * 16 + q4 * 4;

    for (int tile = 0; tile < NPIX / NT; ++tile) {
        // stage V tile (latency hidden under s-MFMA + exp)
        #pragma unroll
        for (int qi = 0; qi < 4; ++qi)
            gl2lds16(vbase + (size_t)(wc + qi * 8 + lrow) * NPIX + tile * NT + glog * 8,
                     &Vs[(wc + qi * 8) * NT]);
        bf16x8 qh2 = qh, ql2 = ql;
        if (tile + 1 < NPIX / NT) {
            const unsigned short* p = qp + (size_t)(tile + 1) * (NT * 64);
            qh2 = *(const bf16x8*)p;
            ql2 = *(const bf16x8*)(p + 32);
        }
        // s-MFMA: identical chain to pass 1 -> bit-identical s, so s <= M
        f32x4 s4 = (f32x4)(0.0f);
        s4 = __builtin_amdgcn_mfma_f32_16x16x32_bf16(qh, khi, s4, 0, 0, 0);
        s4 = __builtin_amdgcn_mfma_f32_16x16x32_bf16(ql, khi, s4, 0, 0, 0);
        s4 = __builtin_amdgcn_mfma_f32_16x16x32_bf16(qh, klo, s4, 0, 0, 0);
        float p0 = __expf(s4[0] - M), p1 = __expf(s4[1] - M);
        float p2 = __expf(s4[2] - M), p3 = __expf(s4[3] - M);
        // unnormalized p -> bf16 -> Ps (the m x n lane transpose for PV)
        ushort4 up;
        up.x = f2bf(p0); up.y = f2bf(p1); up.z = f2bf(p2); up.w = f2bf(p3);
        *(ushort4*)&Ps[(msub * 16 + l15) * PSW + nsub * 16 + q4 * 4] = up;
        __syncthreads();   // A: Ps visible + V gl2lds drained
        // normalized fp32 at_map (drains at barrier B, overlapped with MFMA)
        f32x4 an = { p0 * S, p1 * S, p2 * S, p3 * S };
        *(f32x4*)(at_map + amrow + (size_t)tile * NT) = an;
        // PV: O[c,m] += V[c,n] * p[m,n]
        #pragma unroll
        for (int ks = 0; ks < 2; ++ks) {
            const int pg = ((ks * 4 + q4) ^ (l15 & 7)) * 8;
            bf16x8 a0 = *(const bf16x8*)&Vs[(wc + l15) * NT + pg];
            bf16x8 a1 = *(const bf16x8*)&Vs[(wc + 16 + l15) * NT + pg];
            bf16x8 b0 = *(const bf16x8*)&Ps[l15 * PSW + ks * 32 + q4 * 8];
            bf16x8 b1 = *(const bf16x8*)&Ps[(16 + l15) * PSW + ks * 32 + q4 * 8];
            acc[0][0] = __builtin_amdgcn_mfma_f32_16x16x32_bf16(a0, b0, acc[0][0], 0, 0, 0);
            acc[0][1] = __builtin_amdgcn_mfma_f32_16x16x32_bf16(a0, b1, acc[0][1], 0, 0, 0);
            acc[1][0] = __builtin_amdgcn_mfma_f32_16x16x32_bf16(a1, b0, acc[1][0], 0, 0, 0);
            acc[1][1] = __builtin_amdgcn_mfma_f32_16x16x32_bf16(a1, b1, acc[1][1], 0, 0, 0);
        }
        __syncthreads();   // B: Vs/Ps reusable, at_map stores drained
        qh = qh2; ql = ql2;
    }

    // ---- epilogue: out = x + gamma*inv[m]*O.  D: row=q4*4+r -> c, col -> m -
    const float g = gptr[0];
    const float gi0 = g * IvS[l15], gi1 = g * IvS[16 + l15];
    #pragma unroll
    for (int i = 0; i < 2; ++i) {
        int c = wc + i * 16 + q4 * 4;
        #pragma unroll
        for (int j = 0; j < 2; ++j) {
            int m = m0 + j * 16 + l15;
            float gi = j ? gi1 : gi0;
            #pragma unroll
            for (int r = 0; r < 4; ++r) {
                size_t idx = ((size_t)(b * CIN + c + r)) * NPIX + m;
                out[idx] = x[idx] + gi * acc[i][j][r];
            }
        }
    }
}

// ---------------- Kernel 3 (fallback): fp32 VALU GEMM ----------------------
__global__ __launch_bounds__(256) void sa_gemm_kernel(
    const float* __restrict__ v, const float* __restrict__ at_map,
    const float* __restrict__ x, const float* __restrict__ gptr,
    float* __restrict__ out)
{
    __shared__ float Vt[32][68];
    __shared__ float At[32][68];
    const int t  = threadIdx.x;
    const int m0 = blockIdx.x * 64;
    const int c0 = blockIdx.y * 64;
    const int b  = blockIdx.z;
    const int r  = t >> 2, qd = t & 3;
    const int tc = t & 15, tm = t >> 4;

    const float* vb = v      + ((size_t)(b * CIN  + c0 + r)) * NPIX + qd * 4;
    const float* ab = at_map + ((size_t)(b * NPIX + m0 + r)) * NPIX + qd * 4;

    float acc[4][4];
    #pragma unroll
    for (int i = 0; i < 4; ++i)
        #pragma unroll
        for (int j = 0; j < 4; ++j) acc[i][j] = 0.f;

    for (int n0 = 0; n0 < NPIX; n0 += 32) {
        float4 v0 = *(const float4*)(vb + n0);
        float4 v1 = *(const float4*)(vb + n0 + 16);
        float4 a0 = *(const float4*)(ab + n0);
        float4 a1 = *(const float4*)(ab + n0 + 16);
        Vt[qd*4+0][r] = v0.x; Vt[qd*4+1][r] = v0.y;
        Vt[qd*4+2][r] = v0.z; Vt[qd*4+3][r] = v0.w;
        Vt[16+qd*4+0][r] = v1.x; Vt[16+qd*4+1][r] = v1.y;
        Vt[16+qd*4+2][r] = v1.z; Vt[16+qd*4+3][r] = v1.w;
        At[qd*4+0][r] = a0.x; At[qd*4+1][r] = a0.y;
        At[qd*4+2][r] = a0.z; At[qd*4+3][r] = a0.w;
        At[16+qd*4+0][r] = a1.x; At[16+qd*4+1][r] = a1.y;
        At[16+qd*4+2][r] = a1.z; At[16+qd*4+3][r] = a1.w;
        __syncthreads();
        #pragma unroll
        for (int kk = 0; kk < 32; ++kk) {
            float4 a  = *(const float4*)&Vt[kk][tc * 4];
            float4 bb = *(const float4*)&At[kk][tm * 4];
            acc[0][0] = fmaf(a.x, bb.x, acc[0][0]);
            acc[0][1] = fmaf(a.x, bb.y, acc[0][1]);
            acc[0][2] = fmaf(a.x, bb.z, acc[0][2]);
            acc[0][3] = fmaf(a.x, bb.w, acc[0][3]);
            acc[1][0] = fmaf(a.y, bb.x, acc[1][0]);
            acc[1][1] = fmaf(a.y, bb.y, acc[1][1]);
            acc[1][2] = fmaf(a.y, bb.z, acc[1][2]);
            acc[1][3] = fmaf(a.y, bb.w, acc[1][3]);
            acc[2][0] = fmaf(a.z, bb.x, acc[2][0]);
            acc[2][1] = fmaf(a.z, bb.y, acc[2][1]);
            acc[2][2] = fmaf(a.z, bb.z, acc[2][2]);
            acc[2][3] = fmaf(a.z, bb.w, acc[2][3]);
            acc[3][0] = fmaf(a.w, bb.x, acc[3][0]);
            acc[3][1] = fmaf(a.w, bb.y, acc[3][1]);
            acc[3][2] = fmaf(a.w, bb.z, acc[3][2]);
            acc[3][3] = fmaf(a.w, bb.w, acc[3][3]);
        }
        __syncthreads();
    }

    const float g = *gptr;
    #pragma unroll
    for (int i = 0; i < 4; ++i) {
        size_t row = ((size_t)(b * CIN + c0 + tc * 4 + i)) * NPIX + m0 + tm * 4;
        float4 xv = *(const float4*)(x + row);
        float4 o  = { xv.x + g * acc[i][0], xv.y + g * acc[i][1],
                      xv.z + g * acc[i][2], xv.w + g * acc[i][3] };
        *(float4*)(out + row) = o;
    }
}

extern "C" void kernel_launch(void* const* d_in, const int* in_sizes, int n_in,
                              void* d_out, int out_size, void* d_ws, size_t ws_size,
                              hipStream_t stream) {
    const float* x     = (const float*)d_in[0];
    const float* wq    = (const float*)d_in[1];
    const float* bq    = (const float*)d_in[2];
    const float* wk    = (const float*)d_in[3];
    const float* bk    = (const float*)d_in[4];
    const float* wv    = (const float*)d_in[5];
    const float* bv    = (const float*)d_in[6];
    const float* gamma = (const float*)d_in[7];

    float* out    = (float*)d_out;                   // [B,C,H,W]
    float* at_map = out + (size_t)BSZ * CIN * NPIX;  // [B,N,N] fp32

    const size_t qk_elems = (size_t)BSZ * CQK * NPIX;   // 524288 (fallback fp32)
    const size_t v_elems  = (size_t)BSZ * CIN * NPIX;   // 4194304
    const size_t qt_elems = (size_t)BSZ * NPIX * 64;    // 1048576 shorts

    // fast path: qt + kt (transposed split-bf16) + v bf16
    const size_t need_fast = qt_elems * 2 * 2 + v_elems * 2;   // 12 MB

    if (ws_size >= need_fast) {
        unsigned short* qtp  = (unsigned short*)d_ws;
        unsigned short* ktp  = qtp + qt_elems;
        unsigned short* v_bf = ktp + qt_elems;

        proj_qk_t_kernel<<<dim3(NPIX/512, 8, BSZ), 256, 0, stream>>>(
            x, wq, bq, wk, bk, qtp, ktp);
        proj_v_bf16_kernel<<<dim3(NPIX/512, CIN/16, BSZ), 256, 0, stream>>>(
            x, wv, bv, v_bf);

        fused_attn_mfma<<<dim3(512, 1, 1), 512, 0, stream>>>(
            qtp, ktp, v_bf, x, gamma, at_map, out);
    } else {
        // fallback: all-fp32 split path
        float* q = (float*)d_ws;
        float* k = q + qk_elems;
        float* v = k + qk_elems;

        proj_kernel<<<dim3(NPIX/1024, CQK/8, BSZ), 256, 0, stream>>>(x, wq, bq, q, CQK);
        proj_kernel<<<dim3(NPIX/1024, CQK/8, BSZ), 256, 0, stream>>>(x, wk, bk, k, CQK);
        proj_kernel<<<dim3(NPIX/1024, CIN/8, BSZ), 256, 0, stream>>>(x, wv, bv, v, CIN);

        energy_softmax_kernel<<<dim3(NPIX/8, BSZ), 512, 0, stream>>>(q, k, at_map);

        sa_gemm_kernel<<<dim3(NPIX/64, CIN/64, BSZ), 256, 0, stream>>>(
            v, at_map, x, gamma, out);
    }
}